// Round 8
// baseline (410.019 us; speedup 1.0000x reference)
//
#include <hip/hip_runtime.h>
#include <stdint.h>

// out[(b,m),n] = (sum_k x_q[(b,m),k] * w[n,k]) * sx[(b,m)] * ws[n] + bias[n]
// pass 1: int32 -> packed int8, two one-shot launches (R0 style).
// pass 2: 256x128-tile i8 MFMA GEMM, 4 waves (2x2) of R1's 128x64 wave tiles
//         (12 ds_read + 32 MFMA per wave per K-tile, R1's proven ratios),
//         ring-3 x 24KB = 72KB LDS -> 2 blocks/CU. Each block gives 1 wave
//         per SIMD, so every SIMD hosts 2 waves from INDEPENDENT barrier
//         groups -> one block's MFMA clusters cover the other's read bursts
//         (the anti-phase R6 proved impossible within one barrier group).
//         Counted vmcnt(6) (never drains in-loop), 16B-chunk XOR swizzle
//         (R1's zero-conflict pattern, congruences re-verified for 4 waves).
//         History: R1/R7 = 136-138us @ 44% MfmaUtil (best); R2 reg-dbuf -5;
//         R4 32x32 bank-conflicts -10; R5 64x64 tile -23 (ratio-confounded);
//         R6 in-block phase barriers -4.
#define MROWS 8192
#define K_DIM 4096
#define N_DIM 4096
#define BM 256
#define BN 128
#define BK 64                   // bytes of K per tile
#define KT (K_DIM / BK)         // 64 K-tiles
#define A_BYTES (BM * BK)       // 16 KB
#define B_BYTES (BN * BK)       // 8 KB
#define SLOT (A_BYTES + B_BYTES)// 24 KB per ring slot; ring-3 = 72 KB

#define X_ELEMS (MROWS * K_DIM)
#define W_ELEMS (N_DIM * K_DIM)

typedef __attribute__((ext_vector_type(4))) int   int4v;
typedef __attribute__((ext_vector_type(4))) float float4v;

#define GLOAD_LDS16(gptr, lptr)                                                   \
    __builtin_amdgcn_global_load_lds((const __attribute__((address_space(1))) void*)(gptr), \
                                     (__attribute__((address_space(3))) void*)(lptr), 16, 0, 0)

// ---- pass 1: int32 -> packed int8, 16 elems (64 B read -> 16 B write) / lane --
__device__ __forceinline__ int pack4(int4v v) {
    return (int)((unsigned)(v[0] & 0xFF)
               | ((unsigned)(v[1] & 0xFF) << 8)
               | ((unsigned)(v[2] & 0xFF) << 16)
               | ((unsigned)(v[3] & 0xFF) << 24));
}

__global__ __launch_bounds__(256) void pack_i32_to_i8(
    const int4v* __restrict__ src, int4v* __restrict__ dst, int n16)
{
    int i = blockIdx.x * blockDim.x + threadIdx.x;
    if (i >= n16) return;
    int4v a = src[4 * i + 0];
    int4v b = src[4 * i + 1];
    int4v c = src[4 * i + 2];
    int4v d = src[4 * i + 3];
    int4v r;
    r[0] = pack4(a); r[1] = pack4(b); r[2] = pack4(c); r[3] = pack4(d);
    dst[i] = r;
}

// ---- pass 2: i8 GEMM + dequant epilogue -------------------------------------
// LDS swizzle (per 64B row, 4 x 16B chunks): chunk c of row r stored at slot
// (c + (r>>1)) & 3, realized by pre-swizzling the per-lane GLOBAL source so
// the hardware's linear lane*16 LDS placement lands the permutation.
__global__ __launch_bounds__(256, 2) void i8gemm_dq_kernel(
    const int8_t* __restrict__ xq,   // (8192, 4096) packed i8
    const float*  __restrict__ sx,   // (8192,)
    const int8_t* __restrict__ wt,   // (4096, 4096) packed i8 (row = n)
    const float*  __restrict__ ws,   // (4096,)
    const float*  __restrict__ bias, // (4096,)
    float*        __restrict__ out)  // (8192, 4096) f32
{
    __shared__ __align__(16) int8_t lds8[3 * SLOT];   // 72 KB ring

    const int tid  = threadIdx.x;
    const int wave = tid >> 6;    // 0..3
    const int lane = tid & 63;
    const int wrow = wave >> 1;   // 0..1 : 128-row half of the 256-row tile
    const int wcol = wave & 1;    // 0..1 : 64-col half of the 128-col tile

    // XCD-aware swizzle: 1024 blocks, 8 XCDs, 128 contiguous wgs per XCD.
    // Consecutive wgs share rt (A-panel) for L2 locality.
    const int bid = blockIdx.x;
    const int wg  = (bid & 7) * 128 + (bid >> 3);
    const int ct  = wg & 31;          // 32 col tiles (N/128)
    const int rt  = wg >> 5;          // 32 row tiles (M/256)

    // ---- staging addressing: per call, 4 waves cover 64 rows
    // (row = wave*16 + lane>>2, chunk = lane&3); global chunk fetched =
    // (slot - (row>>1)) & 3 with (row>>1)&3 == (lane>>3)&3 (wave*8, 32k == 0 mod 4).
    const int srow = wave * 16 + (lane >> 2);       // 0..63
    const int scol = (((lane & 3) - ((lane >> 3) & 3)) & 3) * 16;
    const int8_t* gA = xq + (size_t)(rt * BM + srow) * K_DIM + scol;   // + 64k rows
    const int8_t* gB = wt + (size_t)(ct * BN + srow) * K_DIM + scol;   // + 64k rows
    const int dA = wave * 1024;             // + k*4096 (A chunks k=0..3)
    const int dB = A_BYTES + wave * 1024;   // + k*4096 (B chunks k=0..1)

    // ---- fragment read addressing (R1's proven zero-conflict pattern) ----
    const int mrow = lane & 15;
    const int kswz = (((lane >> 4) + (mrow >> 1)) & 3) * 16;
    const int aoff = (wrow * 128 + mrow) * BK + kswz;            // + i*1024, i=0..7
    const int boff = A_BYTES + (wcol * 64 + mrow) * BK + kswz;   // + j*1024, j=0..3

    int4v acc[8][4] = {};   // 8x4 of 16x16 int32 accumulators per wave

#define STAGE_A012(U, S)                                       \
    {                                                          \
        const size_t ko_ = (size_t)(U) * BK;                   \
        int8_t* bb_ = lds8 + (S) * SLOT;                       \
        GLOAD_LDS16(gA + ko_,                   bb_ + dA);     \
        GLOAD_LDS16(gA +  64 * K_DIM + ko_, bb_ + dA + 4096);  \
        GLOAD_LDS16(gA + 128 * K_DIM + ko_, bb_ + dA + 8192);  \
    }
#define STAGE_A3B(U, S)                                        \
    {                                                          \
        const size_t ko_ = (size_t)(U) * BK;                   \
        int8_t* bb_ = lds8 + (S) * SLOT;                       \
        GLOAD_LDS16(gA + 192 * K_DIM + ko_, bb_ + dA + 12288); \
        GLOAD_LDS16(gB + ko_,                   bb_ + dB);     \
        GLOAD_LDS16(gB +  64 * K_DIM + ko_, bb_ + dB + 4096);  \
    }

    // prologue: stage tiles 0,1 into slots 0,1 -> 12 loads/wave in flight
    STAGE_A012(0, 0); STAGE_A3B(0, 0);
    STAGE_A012(1, 1); STAGE_A3B(1, 1);

    // main loop: land tile t (vmcnt(6): tile t+1's 6 stay in flight),
    // stage tile t+2 into slot (t+2)%3 (last read at t-1, certified dead by
    // this tile's barrier), compute tile t. R1's two-phase body ordering.
    #pragma unroll 3
    for (int t = 0; t < KT - 2; ++t) {
        const int8_t* base = lds8 + (t % 3) * SLOT;
        const int s2 = (t + 2) % 3;

        asm volatile("s_waitcnt vmcnt(6)" ::: "memory");   // tile t landed
        __builtin_amdgcn_s_barrier();
        __builtin_amdgcn_sched_barrier(0);

        // phase 0: rows wrow*128 + 0..63
        int4v a[4], b[4];
        #pragma unroll
        for (int i = 0; i < 4; ++i) a[i] = *(const int4v*)(base + aoff + i * 1024);
        #pragma unroll
        for (int j = 0; j < 4; ++j) b[j] = *(const int4v*)(base + boff + j * 1024);
        STAGE_A012(t + 2, s2);

        __builtin_amdgcn_s_setprio(1);
        #pragma unroll
        for (int i = 0; i < 4; ++i)
            #pragma unroll
            for (int j = 0; j < 4; ++j)
                acc[i][j] = __builtin_amdgcn_mfma_i32_16x16x64_i8(
                                a[i], b[j], acc[i][j], 0, 0, 0);
        __builtin_amdgcn_s_setprio(0);

        // phase 1: rows wrow*128 + 64..127 (B frags reused)
        int4v a2[4];
        #pragma unroll
        for (int i = 0; i < 4; ++i) a2[i] = *(const int4v*)(base + aoff + (4 + i) * 1024);
        STAGE_A3B(t + 2, s2);

        __builtin_amdgcn_s_setprio(1);
        #pragma unroll
        for (int i = 0; i < 4; ++i)
            #pragma unroll
            for (int j = 0; j < 4; ++j)
                acc[4 + i][j] = __builtin_amdgcn_mfma_i32_16x16x64_i8(
                                    a2[i], b[j], acc[4 + i][j], 0, 0, 0);
        __builtin_amdgcn_s_setprio(0);
    }

    // tail: tiles KT-2 (KT-1's loads still in flight) and KT-1 (full drain)
    #pragma unroll
    for (int e = 0; e < 2; ++e) {
        const int t = KT - 2 + e;
        const int8_t* base = lds8 + (t % 3) * SLOT;
        if (e == 0) asm volatile("s_waitcnt vmcnt(6)" ::: "memory");
        else        asm volatile("s_waitcnt vmcnt(0)" ::: "memory");
        __builtin_amdgcn_s_barrier();
        __builtin_amdgcn_sched_barrier(0);
        int4v a[4], b[4], a2[4];
        #pragma unroll
        for (int i = 0; i < 4; ++i) a[i]  = *(const int4v*)(base + aoff + i * 1024);
        #pragma unroll
        for (int j = 0; j < 4; ++j) b[j]  = *(const int4v*)(base + boff + j * 1024);
        #pragma unroll
        for (int i = 0; i < 4; ++i) a2[i] = *(const int4v*)(base + aoff + (4 + i) * 1024);
        __builtin_amdgcn_s_setprio(1);
        #pragma unroll
        for (int i = 0; i < 4; ++i)
            #pragma unroll
            for (int j = 0; j < 4; ++j)
                acc[i][j] = __builtin_amdgcn_mfma_i32_16x16x64_i8(
                                a[i], b[j], acc[i][j], 0, 0, 0);
        #pragma unroll
        for (int i = 0; i < 4; ++i)
            #pragma unroll
            for (int j = 0; j < 4; ++j)
                acc[4 + i][j] = __builtin_amdgcn_mfma_i32_16x16x64_i8(
                                    a2[i], b[j], acc[4 + i][j], 0, 0, 0);
        __builtin_amdgcn_s_setprio(0);
    }

#undef STAGE_A012
#undef STAGE_A3B

    // ---- epilogue: C/D layout col=lane&15, row=(lane>>4)*4+reg ----
    const int row_base = rt * BM + wrow * 128;
    const int col_base = ct * BN + wcol * 64;
    const int crow = (lane >> 4) * 4;
    const int ccol = lane & 15;

    float wsc[4], bsc[4];
    #pragma unroll
    for (int j = 0; j < 4; ++j) {
        const int c = col_base + j * 16 + ccol;
        wsc[j] = ws[c];
        bsc[j] = bias[c];
    }

    #pragma unroll
    for (int i = 0; i < 8; ++i) {
        const int r0 = row_base + i * 16 + crow;
        const float4v sx4 = *(const float4v*)(sx + r0);
        #pragma unroll
        for (int j = 0; j < 4; ++j) {
            const int c = col_base + j * 16 + ccol;
            float* o = out + (size_t)r0 * N_DIM + c;
            #pragma unroll
            for (int r = 0; r < 4; ++r)
                o[(size_t)r * N_DIM] = (float)acc[i][j][r] * sx4[r] * wsc[j] + bsc[j];
        }
    }
}

extern "C" void kernel_launch(void* const* d_in, const int* in_sizes, int n_in,
                              void* d_out, int out_size, void* d_ws, size_t ws_size,
                              hipStream_t stream) {
    const int*   xq32 = (const int*)d_in[0];
    const float* sx   = (const float*)d_in[1];
    const int*   wt32 = (const int*)d_in[2];
    const float* ws   = (const float*)d_in[3];
    const float* bias = (const float*)d_in[4];
    float* out = (float*)d_out;

    int8_t* xq8 = (int8_t*)d_ws;
    int8_t* wt8 = xq8 + (size_t)X_ELEMS;

    {
        int n16x = X_ELEMS / 16;
        int n16w = W_ELEMS / 16;
        pack_i32_to_i8<<<n16x / 256, 256, 0, stream>>>((const int4v*)xq32, (int4v*)xq8, n16x);
        pack_i32_to_i8<<<n16w / 256, 256, 0, stream>>>((const int4v*)wt32, (int4v*)wt8, n16w);
    }

    dim3 grid((MROWS / BM) * (N_DIM / BN));  // 1024 blocks
    i8gemm_dq_kernel<<<grid, 256, 0, stream>>>(xq8, sx, wt8, ws, bias, out);
}